// Round 3
// baseline (10487.299 us; speedup 1.0000x reference)
//
#include <hip/hip_runtime.h>
#include <math.h>
#include <float.h>

#define BN   2
#define NPTS 16384
#define MPTS 4096
#define KGN  32
#define CIN  64
#define CLN  64

// ---------- exact fp32 helpers (no FMA contraction; must match np fp32) ----------
__device__ __forceinline__ float exadd(float a, float b) {
#pragma clang fp contract(off)
    float r = a + b; return r;
}
__device__ __forceinline__ float exsub(float a, float b) {
#pragma clang fp contract(off)
    float r = a - b; return r;
}
__device__ __forceinline__ float exmul(float a, float b) {
#pragma clang fp contract(off)
    float r = a * b; return r;
}

__device__ __forceinline__ float wave_sum64(float v) {
#pragma unroll
    for (int off = 1; off < 64; off <<= 1) v += __shfl_xor(v, off);
    return v;
}

// =====================================================================
// K0: pack points as float4(x, y, z, ||p||^2) once. sb order matches
// jnp.sum(b*b,-1): ((x*x + y*y) + z*z), contract off. Values verbatim.
// =====================================================================
__global__ __launch_bounds__(256) void prep_kernel(const float* __restrict__ xyz,
                                                   float4* __restrict__ pts4) {
    const int i = blockIdx.x * 256 + threadIdx.x;   // 0 .. BN*NPTS-1
    const float x = xyz[3 * i + 0];
    const float y = xyz[3 * i + 1];
    const float z = xyz[3 * i + 2];
    const float sb = exadd(exadd(exmul(x, x), exmul(y, y)), exmul(z, z));
    pts4[i] = make_float4(x, y, z, sb);
}

// =====================================================================
// K1: FPS — R6: R1's proven scalar distance loop (6726 us) + minimal
// reduction plumbing: ONE barrier, ONE ds_max_u64 per wave, ONE
// broadcast ds_read_b64 + ONE broadcast ds_read_b128 per thread.
// Value chain is verbatim-equivalent to the passing kernel:
//   d = (dx*dx + dy*dy) + dz*dz  (fp32, no contraction),
//   dist = fminf(dist, d), init 1e10, start index 0,
//   argmax tie-break = first occurrence (smallest global index).
//
// Per iteration m (cur = m%3):
//   A-phase (before the barrier):
//     1. dist update with (cx,cy,cz); per-thread lmax (16 fmaxf chain)
//     2. f32 wave max (6x shfl_xor+fmax)
//     3. cand = ballot(lmax==wmax); first candidate lane only:
//        sel-scan (descending: final hit = smallest i), pack
//        pk = (bits(wmax)<<32) | (0xFFFFFFFF - gidx),
//        atomicMax(&slot[cur], pk)  [ds_max_u64],
//        scoord[cur][wid] = candidate coords [ds_write_b128].
//        First candidate lane owns the wave's smallest global index:
//        lane t owns contiguous ids t*16..t*16+15 (ascending in lane),
//        and within the lane sel is the smallest matching i. u64 max
//        across waves = (max dist bits, then min index) == reference
//        first-occurrence argmax (dist >= 0 so f32 bits are monotone).
//   B-phase (after the ONLY barrier):
//     4. w = slot[cur]           (ds_read_b64, same addr -> broadcast)
//     5. t0: slot[(m+2)%3] = 0   (reset the slot READ at iter m-1)
//     6. gidx = 0xFFFFFFFF - lo32(w); coords = scoord[cur][gidx>>10]
//        (ds_read_b128 broadcast); t0 stores out_idx[m+? ] -- see loop.
//
// Race-freedom with ONE barrier (period-3 slots):
//   slot S=m%3: written A(m) [pre-B1(m)], read B(m) [post-B1(m)],
//   reset at B(m+1) (slot[(m+1+2)%3] == slot[m%3]), next written A(m+3).
//   * reset vs reads: all B(m) reads precede B1(m+1); reset is after
//     B1(m+1). OK.
//   * reset vs next writes: writers reach A(m+3) only after passing
//     B1(m+2); t0 passed B1(m+2) after performing the reset (program
//     order: reset in B(m+1), then iter m+2's A-phase, then B1(m+2)).
//     OK.
//   scoord[cur][wid]: each wave's firstlane fully overwrites its own
//   wid slot in A(m); read B(m); next write A(m+3) > B1(m+2) > all
//   B(m) reads. No reset needed. Winner's wid slot was written THIS
//   iteration because the block winner is its own wave's first
//   candidate lane. OK.
// =====================================================================
__global__ __attribute__((amdgpu_waves_per_eu(4, 4)))
__launch_bounds__(1024) void fps_kernel(const float4* __restrict__ P4,
                                        int* __restrict__ out_idx) {
    const int b = blockIdx.x;
    const int t = threadIdx.x;
    const int lane = t & 63;
    const int wid  = t >> 6;
    const float4* P = P4 + (size_t)b * NPTS;

    float px[16], py[16], pz[16], dist[16];
#pragma unroll
    for (int i = 0; i < 16; ++i) {
        float4 a = P[t * 16 + i];
        px[i] = a.x;
        py[i] = a.y;
        pz[i] = a.z;
        dist[i] = 1e10f;
    }
#pragma unroll
    for (int i = 0; i < 16; ++i) {
        asm volatile("" : "+v"(px[i]), "+v"(py[i]), "+v"(pz[i]));
    }

    __shared__ unsigned long long slot[3];
    __shared__ float4 scoord[3][16];

    if (t < 3) slot[t] = 0ull;
    __syncthreads();

    // centroid 0 = point 0 (uniform scalar load; matches reference far=0)
    float cx, cy, cz;
    {
        const float4 C0 = P[0];
        cx = C0.x; cy = C0.y; cz = C0.z;
    }
    int cgidx = 0;
    int cur = 0;   // m % 3

    for (int m = 0; m < MPTS; ++m) {
        if (t == 0) out_idx[b * MPTS + m] = cgidx;   // fire-and-forget

        float lmax = -1.0f;
#pragma unroll
        for (int i = 0; i < 16; ++i) {
            float dx = exsub(px[i], cx);
            float dy = exsub(py[i], cy);
            float dz = exsub(pz[i], cz);
            float d  = exadd(exadd(exmul(dx, dx), exmul(dy, dy)), exmul(dz, dz));
            float nd = fminf(dist[i], d);
            dist[i] = nd;
            lmax = fmaxf(lmax, nd);
        }

        // f32 wave max
        float wmax = lmax;
#pragma unroll
        for (int off = 1; off < 64; off <<= 1) wmax = fmaxf(wmax, __shfl_xor(wmax, off));

        // first candidate lane == wave's smallest global index among maxima
        const unsigned long long cand = __ballot(lmax == wmax);
        const int firstlane = __ffsll(cand) - 1;
        if (lane == firstlane) {
            int sel = 0;
#pragma unroll
            for (int i = 15; i >= 0; --i) {          // descending: final hit = smallest i
                if (dist[i] == lmax) sel = i;
            }
            const unsigned gidx = (unsigned)(t * 16 + sel);
            const unsigned long long pk =
                ((unsigned long long)__float_as_uint(wmax) << 32) |
                (unsigned long long)(0xFFFFFFFFu - gidx);
            atomicMax(&slot[cur], pk);
            scoord[cur][wid] = make_float4(px[sel], py[sel], pz[sel], 0.0f);
        }

        __syncthreads();                              // the ONLY barrier

        const unsigned long long w = slot[cur];       // broadcast ds_read_b64
        // reset the slot that was read at iter m-1 (safe: see header proof)
        if (t == 0) slot[cur == 0 ? 2 : cur - 1] = 0ull;

        const unsigned gidx = 0xFFFFFFFFu - (unsigned)(w & 0xFFFFFFFFull);
        const float4 C = scoord[cur][gidx >> 10];     // broadcast ds_read_b128
        cx = C.x; cy = C.y; cz = C.z;
        cgidx = (int)gidx;

        cur = (cur == 2) ? 0 : cur + 1;
    }
}

// =====================================================================
// K2: exact 32-NN, wave per centroid, NO per-lane arrays (R3 spilled
// its key[32]/nid[32] to scratch: 18.9 GB FETCH / 12.6 GB WRITE).
// Wave-wide sorted top-32 lives in ONE (key,idx) register pair per
// lane (lanes 0..31, ascending (key,idx) lex). Candidates found via
// ballot; each inserted exactly: p = popc(ballot(lex-less)), shift
// lanes >= p up by one, lane p takes the candidate.
// Exactness: selection by (key,idx) lex = lax.top_k stable set; insert
// order irrelevant (final content = top-32 of union). Keys use R3's
// exact chain: d2 = (sa+sb) - 2*dot, key = fmaxf(d2,0).
// Radius pre-filter sqrtf(dk)<=0.8f is set-equivalent: the radius set
// is down-closed in key order, so top32(all) ∩ radius == top32(radius)
// (proof: if >=32 in-radius, the 32 global-nearest all have key <= the
// in-radius 32nd key, hence in-radius; else all in-radius points are
// among the global top-32). Sentinels (FLT_MAX, idx 0) fail the mask
// in mlp and idx 0 is a safe gather.
// =====================================================================
__global__ __launch_bounds__(256) void knn_kernel(const float4* __restrict__ pts4,
                                                  const int* __restrict__ fps_idx,
                                                  float* __restrict__ newxyz,
                                                  int* __restrict__ nn_idx,
                                                  float* __restrict__ nn_key) {
    const int lane = threadIdx.x & 63;
    const int g    = blockIdx.x * 4 + (threadIdx.x >> 6);   // centroid 0..8191
    const int b    = g >> 12;
    const float4* P = pts4 + (size_t)b * NPTS;

    const int far = fps_idx[g];
    const float4 C = P[far];
    if (lane == 0) {
        newxyz[g * 3 + 0] = C.x;
        newxyz[g * 3 + 1] = C.y;
        newxyz[g * 3 + 2] = C.z;
    }
    const float sa = C.w;

    float skey = FLT_MAX;   // lanes 0..31: sorted entries; lanes 32..63: inert
    int   sidx = 0;

    for (int it = 0; it < NPTS / 64; ++it) {
        const int j = it * 64 + lane;
        const float4 Q = P[j];
        const float dot = exadd(exadd(exmul(C.x, Q.x), exmul(C.y, Q.y)), exmul(C.z, Q.z));
        const float d2  = exsub(exadd(sa, Q.w), exadd(dot, dot));
        const float dk  = fmaxf(d2, 0.0f);
        // current 32nd-best (tau) from lane 31 — stale within the iteration is
        // fine: the insert itself recomputes the exact position.
        const float tk = __shfl(skey, 31);
        const int   ti = __shfl(sidx, 31);
        const bool pass = (sqrtf(dk) <= 0.8f) &&
                          ((dk < tk) || (dk == tk && j < ti));
        unsigned long long mask = __ballot(pass);
        while (mask) {
            const int src = __ffsll(mask) - 1;
            mask &= mask - 1;
            const float ck = __shfl(dk, src);
            const int   cj = it * 64 + src;
            const bool less = (skey < ck) || (skey == ck && sidx < cj);
            const int p = __popcll(__ballot(less));   // wave-uniform rank
            if (p < 32) {                              // wave-uniform branch
                const float upk = __shfl_up(skey, 1);
                const int   upi = __shfl_up(sidx, 1);
                if (lane < 32) {
                    if (lane == p)     { skey = ck;  sidx = cj; }
                    else if (lane > p) { skey = upk; sidx = upi; }
                }
            }
        }
    }
    if (lane < KGN) {
        nn_idx[(size_t)g * KGN + lane] = sidx;
        nn_key[(size_t)g * KGN + lane] = skey;
    }
}

// =====================================================================
// K3: shared MLP 3->32->32->64 (+BN affine +ReLU), radius mask via
// sqrtf(nn_key) <= 0.8 (R3 verbatim), max over 32 neighbors.
// waves_per_eu(4,4): h1+h2 = 64 live floats — same spill class as knn;
// raise budget to 128 (value-neutral).
// =====================================================================
__global__ __attribute__((amdgpu_waves_per_eu(4, 4)))
__launch_bounds__(256) void mlp_kernel(const float* __restrict__ xyz,
                                       const float* __restrict__ w1, const float* __restrict__ s1, const float* __restrict__ b1,
                                       const float* __restrict__ w2, const float* __restrict__ s2, const float* __restrict__ b2,
                                       const float* __restrict__ w3, const float* __restrict__ s3, const float* __restrict__ b3,
                                       const float* __restrict__ newxyz,
                                       const int* __restrict__ nn_idx,
                                       const float* __restrict__ nn_key,
                                       float* __restrict__ FLout) {
    __shared__ float W1[96], S1[32], B1[32];
    __shared__ float W2[1024], S2[32], B2[32];
    __shared__ float W3[2048], S3[64], B3[64];
    const int tid = threadIdx.x;
    for (int i = tid; i < 96; i += 256)   W1[i] = w1[i];
    for (int i = tid; i < 32; i += 256) { S1[i] = s1[i]; B1[i] = b1[i]; S2[i] = s2[i]; B2[i] = b2[i]; }
    for (int i = tid; i < 1024; i += 256) W2[i] = w2[i];
    for (int i = tid; i < 2048; i += 256) W3[i] = w3[i];
    for (int i = tid; i < 64; i += 256) { S3[i] = s3[i]; B3[i] = b3[i]; }
    __syncthreads();

    const int n  = tid & 31;
    const int g  = blockIdx.x * 8 + (tid >> 5);   // centroid 0..8191
    const int b  = g >> 12;
    const size_t base = (size_t)g * KGN + n;
    const int   nj = nn_idx[base];
    const float nk = nn_key[base];

    const float* X = xyz + (size_t)b * NPTS * 3;
    const float gx = X[nj * 3 + 0] - newxyz[g * 3 + 0];
    const float gy = X[nj * 3 + 1] - newxyz[g * 3 + 1];
    const float gz = X[nj * 3 + 2] - newxyz[g * 3 + 2];

    float h1[32];
#pragma unroll
    for (int o = 0; o < 32; ++o) {
        float a = gx * W1[o * 3 + 0] + gy * W1[o * 3 + 1] + gz * W1[o * 3 + 2];
        h1[o] = fmaxf(a * S1[o] + B1[o], 0.0f);
    }
    float h2[32];
#pragma unroll
    for (int o = 0; o < 32; ++o) {
        float a = 0.0f;
#pragma unroll
        for (int k = 0; k < 32; ++k) a += h1[k] * W2[o * 32 + k];
        h2[o] = fmaxf(a * S2[o] + B2[o], 0.0f);
    }
    const bool valid = (sqrtf(nk) <= 0.8f);   // exact mask (sentinel FLT_MAX -> false)

    for (int o = 0; o < 64; ++o) {
        float a = 0.0f;
#pragma unroll
        for (int k = 0; k < 32; ++k) a += h2[k] * W3[o * 32 + k];
        float v = fmaxf(a * S3[o] + B3[o], 0.0f);
        v = valid ? v : -INFINITY;
#pragma unroll
        for (int off = 1; off < 32; off <<= 1) v = fmaxf(v, __shfl_xor(v, off));
        if (n == (o & 31)) FLout[(size_t)g * CLN + o] = v;
    }
}

// =====================================================================
// K4: DAM fusion (R3 verbatim). Wave per centroid, lane = channel.
// LDS-transposed 64x64 weights for conflict-free per-lane reads.
// =====================================================================
__global__ __launch_bounds__(256) void fuse_kernel(const float* __restrict__ pts_cam,
                                                   const float* __restrict__ FIn,
                                                   const float* __restrict__ tw1, const float* __restrict__ tb1,
                                                   const float* __restrict__ tw2, const float* __restrict__ tb2,
                                                   const float* __restrict__ tw3, const float* __restrict__ tb3,
                                                   const float* __restrict__ gw_raw, const float* __restrict__ gb_raw,
                                                   const float* __restrict__ gw_img, const float* __restrict__ gb_img,
                                                   const float* __restrict__ gw_lid, const float* __restrict__ gb_lid,
                                                   const float* __restrict__ uw, const float* __restrict__ ub,
                                                   const float* __restrict__ vw, const float* __restrict__ vb,
                                                   const int* __restrict__ fps_idx,
                                                   const float* __restrict__ newxyz,
                                                   const float* __restrict__ FLin,
                                                   float* __restrict__ out) {
    __shared__ float WIm[4096], WLi[4096], WT2[4096];
    const int tid = threadIdx.x;
    for (int i = tid; i < 4096; i += 256) {
        int c = i >> 6, k = i & 63;          // weight[c][k] -> transposed [k][c]
        WIm[k * 64 + c] = gw_img[i];
        WLi[k * 64 + c] = gw_lid[i];
        WT2[k * 64 + c] = tw2[i];
    }
    __syncthreads();

    const int lane = tid & 63;
    const int g    = blockIdx.x * 4 + (tid >> 6);   // centroid 0..8191
    const int b    = g >> 12;
    const int m    = g & (MPTS - 1);
    const int far  = fps_idx[g];

    const float fi_in = FIn[((size_t)(b * CIN + lane)) * NPTS + far];
    const float fl_in = FLin[(size_t)g * CLN + lane];
    const float nx = newxyz[g * 3 + 0], ny = newxyz[g * 3 + 1], nz = newxyz[g * 3 + 2];

    float fr = fmaxf(nx * gw_raw[lane * 3 + 0] + ny * gw_raw[lane * 3 + 1] +
                     nz * gw_raw[lane * 3 + 2] + gb_raw[lane], 0.0f);

    float ai = gb_img[lane], al = gb_lid[lane];
#pragma unroll 8
    for (int k = 0; k < 64; ++k) {
        float vi = __shfl(fi_in, k);
        float vl = __shfl(fl_in, k);
        ai += vi * WIm[k * 64 + lane];
        al += vl * WLi[k * 64 + lane];
    }
    const float s = tanhf(fr + fmaxf(ai, 0.0f) + fmaxf(al, 0.0f));

    // AdaptiveThresholdNet on constant density
    const float dens = (float)(64.0 / (4.0 / 3.0 * 3.14159 * 1.0));
    float t1 = fmaxf(dens * tw1[lane] + tb1[lane], 0.0f);
    float a2 = tb2[lane];
#pragma unroll 8
    for (int k = 0; k < 64; ++k) a2 += __shfl(t1, k) * WT2[k * 64 + lane];
    float t2 = fmaxf(a2, 0.0f);
    float a3 = wave_sum64(t2 * tw3[lane]) + tb3[0];
    float thr = 20.0f + 40.0f * (1.0f / (1.0f + expf(-a3)));

    float aI = wave_sum64(s * uw[lane]) + ub[0];
    float aL = wave_sum64(s * vw[lane]) + vb[0];
    float wIv = 1.0f / (1.0f + expf(-aI));
    float wLv = 1.0f / (1.0f + expf(-aL));

    const float z = pts_cam[((size_t)b * NPTS + far) * 3 + 2];
    const bool near = (z <= thr);

    const size_t o1 = ((size_t)(b * 128 + lane)) * MPTS + m;
    out[o1]                       = near ? fl_in        : fi_in;
    out[o1 + (size_t)64 * MPTS]   = near ? fi_in * wIv  : fl_in * wLv;
}

// =====================================================================
extern "C" void kernel_launch(void* const* d_in, const int* in_sizes, int n_in,
                              void* d_out, int out_size, void* d_ws, size_t ws_size,
                              hipStream_t stream) {
    const float* xyz     = (const float*)d_in[0];
    const float* pts_cam = (const float*)d_in[1];
    const float* FI      = (const float*)d_in[2];
    const float* w1 = (const float*)d_in[3];
    const float* s1 = (const float*)d_in[4];
    const float* b1 = (const float*)d_in[5];
    const float* w2 = (const float*)d_in[6];
    const float* s2 = (const float*)d_in[7];
    const float* b2 = (const float*)d_in[8];
    const float* w3 = (const float*)d_in[9];
    const float* s3 = (const float*)d_in[10];
    const float* b3 = (const float*)d_in[11];
    const float* tw1 = (const float*)d_in[12];
    const float* tb1 = (const float*)d_in[13];
    const float* tw2 = (const float*)d_in[14];
    const float* tb2 = (const float*)d_in[15];
    const float* tw3 = (const float*)d_in[16];
    const float* tb3 = (const float*)d_in[17];
    const float* gw_raw = (const float*)d_in[18];
    const float* gb_raw = (const float*)d_in[19];
    const float* gw_img = (const float*)d_in[20];
    const float* gb_img = (const float*)d_in[21];
    const float* gw_lid = (const float*)d_in[22];
    const float* gb_lid = (const float*)d_in[23];
    const float* uw = (const float*)d_in[24];
    const float* ub = (const float*)d_in[25];
    const float* vw = (const float*)d_in[26];
    const float* vb = (const float*)d_in[27];
    float* out = (float*)d_out;

    // workspace layout (bytes) — total 4,325,376.
    // pts4 is dead after knn; FL (written by mlp, later) aliases its region.
    char* ws = (char*)d_ws;
    int*    ws_idx    = (int*)   (ws + 0);         // 8192 ints    (32 KB)
    float*  ws_newxyz = (float*) (ws + 32768);     // 24576 f      (96 KB)  -> 131072
    float4* ws_pts4   = (float4*)(ws + 131072);    // 32768 float4 (512 KB) -> 655360 [dead after knn]
    float*  ws_FL     = (float*) (ws + 131072);    // 524288 f     (2 MB)   -> 2228224 [aliases pts4]
    int*    ws_nnidx  = (int*)   (ws + 2228224);   // 262144 ints  (1 MB)   -> 3276800
    float*  ws_nnkey  = (float*) (ws + 3276800);   // 262144 f     (1 MB)   -> 4325376
    (void)ws_size; (void)in_sizes; (void)n_in; (void)out_size;

    prep_kernel<<<(BN * NPTS) / 256, 256, 0, stream>>>(xyz, ws_pts4);
    fps_kernel<<<BN, 1024, 0, stream>>>(ws_pts4, ws_idx);
    knn_kernel<<<2048, 256, 0, stream>>>(ws_pts4, ws_idx, ws_newxyz, ws_nnidx, ws_nnkey);
    mlp_kernel<<<1024, 256, 0, stream>>>(xyz, w1, s1, b1, w2, s2, b2, w3, s3, b3,
                                         ws_newxyz, ws_nnidx, ws_nnkey, ws_FL);
    fuse_kernel<<<2048, 256, 0, stream>>>(pts_cam, FI, tw1, tb1, tw2, tb2, tw3, tb3,
                                          gw_raw, gb_raw, gw_img, gb_img, gw_lid, gb_lid,
                                          uw, ub, vw, vb, ws_idx, ws_newxyz, ws_FL, out);
}

// Round 5
// 7536.358 us; speedup vs baseline: 1.3916x; 1.3916x over previous
//
#include <hip/hip_runtime.h>
#include <math.h>
#include <float.h>

#define BN   2
#define NPTS 16384
#define MPTS 4096
#define KGN  32
#define CIN  64
#define CLN  64

// ---------- exact fp32 helpers (no FMA contraction; must match np fp32) ----------
__device__ __forceinline__ float exadd(float a, float b) {
#pragma clang fp contract(off)
    float r = a + b; return r;
}
__device__ __forceinline__ float exsub(float a, float b) {
#pragma clang fp contract(off)
    float r = a - b; return r;
}
__device__ __forceinline__ float exmul(float a, float b) {
#pragma clang fp contract(off)
    float r = a * b; return r;
}

__device__ __forceinline__ float wave_sum64(float v) {
#pragma unroll
    for (int off = 1; off < 64; off <<= 1) v += __shfl_xor(v, off);
    return v;
}

// =====================================================================
// K0: pack points as float4(x, y, z, ||p||^2) once. sb order matches
// jnp.sum(b*b,-1): ((x*x + y*y) + z*z), contract off. Values verbatim.
// =====================================================================
__global__ __launch_bounds__(256) void prep_kernel(const float* __restrict__ xyz,
                                                   float4* __restrict__ pts4) {
    const int i = blockIdx.x * 256 + threadIdx.x;   // 0 .. BN*NPTS-1
    const float x = xyz[3 * i + 0];
    const float y = xyz[3 * i + 1];
    const float z = xyz[3 * i + 2];
    const float sb = exadd(exadd(exmul(x, x), exmul(y, y)), exmul(z, z));
    pts4[i] = make_float4(x, y, z, sb);
}

// =====================================================================
// K1: FPS — R7: R1's PROVEN plumbing (best measured 6726us), spill fix.
// Diagnosis: VGPR_Count was 52-60 in R1-R3 => the 64-float/thread
// working set NEVER fit; px/py/pz were spilled to scratch and reloaded
// every iteration (~768 VMEM instr/iter/CU — the dominant cost, and
// the source of the anomalous 263MB FETCH_SIZE).
// Fix: 512 threads x 32 pts/thread with __launch_bounds__(512, 2):
// 8-wave block at 2 waves/EU => VGPR cap 256; working set (128 array
// floats + temps ~ 160 VGPRs) fits with slack => no spills.
// Value chain is verbatim-equivalent to the passing kernel:
//   d = (dx*dx + dy*dy) + dz*dz  (fp32, no contraction),
//   dist = fminf(dist, d), init 1e10, start index 0,
//   argmax tie-break = first occurrence (smallest global index).
// Ownership is STRIDED: thread t owns gidx = i*512 + t (i=0..31) so
// the initial load is fully coalesced. Tie-break stays exact:
//   * within thread: gidx ascending in i; descending scan => smallest i
//     with dist==bm => thread's smallest matching global index;
//   * across threads: atomicMin over explicit global indices.
// bm is bit-exact (fmaxf tree of exact values returns one of them;
// dists >= +0.0, no NaN), so dist==bm is a bit comparison that matches
// at least one thread.
// swidx ping-pong reset ordering (R1-proven): reset of slot (m+1)&1
// sits between B1(m) and B2(m); its readers finished before B1(m);
// its next writers start after B1(m+1) > B2(m) > reset. No race.
// =====================================================================
__global__ __launch_bounds__(512, 2) void fps_kernel(const float4* __restrict__ P4,
                                                     int* __restrict__ out_idx) {
    const int b = blockIdx.x;
    const int t = threadIdx.x;
    const float4* P = P4 + (size_t)b * NPTS;

    float px[32], py[32], pz[32], dist[32];
#pragma unroll
    for (int i = 0; i < 32; ++i) {
        float4 a = P[i * 512 + t];          // coalesced: lane-consecutive
        px[i] = a.x;
        py[i] = a.y;
        pz[i] = a.z;
        dist[i] = 1e10f;
    }
#pragma unroll
    for (int i = 0; i < 32; ++i) {
        asm volatile("" : "+v"(px[i]), "+v"(py[i]), "+v"(pz[i]));
    }

    __shared__ float smax[8];
    __shared__ int   swidx[2];

    if (t == 0) { swidx[0] = 0x7FFFFFFF; swidx[1] = 0x7FFFFFFF; }
    __syncthreads();

    int cidx = 0;   // current centroid index == out_idx[m] (reference: far starts at 0)

    for (int m = 0; m < MPTS; ++m) {
        if (t == 0) out_idx[b * MPTS + m] = cidx;   // fire-and-forget store

        // scalar broadcast load of the centroid (uniform address -> s_load)
        const int ci = __builtin_amdgcn_readfirstlane(cidx);
        const float4 C = P[ci];
        const float cx = C.x, cy = C.y, cz = C.z;

        float lmax = -1.0f;
#pragma unroll
        for (int i = 0; i < 32; ++i) {
            float dx = exsub(px[i], cx);
            float dy = exsub(py[i], cy);
            float dz = exsub(pz[i], cz);
            float d  = exadd(exadd(exmul(dx, dx), exmul(dy, dy)), exmul(dz, dz));
            float nd = fminf(dist[i], d);
            dist[i] = nd;
            lmax = fmaxf(lmax, nd);
        }

        // wave-level f32 max
        float wmax = lmax;
#pragma unroll
        for (int off = 1; off < 64; off <<= 1) wmax = fmaxf(wmax, __shfl_xor(wmax, off));
        if ((t & 63) == 0) smax[t >> 6] = wmax;

        __syncthreads();                               // B1

        // reset the slot used NEXT iteration (ordering: see header proof)
        if (t == 0) swidx[(m + 1) & 1] = 0x7FFFFFFF;

        // block max — replicated parallel reduce, every thread ends with bm
        float bm = smax[t & 7];
#pragma unroll
        for (int off = 1; off < 8; off <<= 1) bm = fmaxf(bm, __shfl_xor(bm, off));

        // candidates publish min global index (exact first-index tie-break)
        if (lmax == bm) {
            int sel = 0;
#pragma unroll
            for (int i = 31; i >= 0; --i) {            // descending: final hit = smallest i
                if (dist[i] == bm) sel = i;
            }
            atomicMin(&swidx[m & 1], sel * 512 + t);
        }

        __syncthreads();                               // B2
        cidx = swidx[m & 1];
    }
}

// =====================================================================
// K2: exact 32-NN, wave per centroid, NO per-lane arrays (R3 spilled
// its key[32]/nid[32] to scratch: 18.9 GB FETCH / 12.6 GB WRITE).
// Wave-wide sorted top-32 lives in ONE (key,idx) register pair per
// lane (lanes 0..31, ascending (key,idx) lex). Candidates found via
// ballot; each inserted exactly: p = popc(ballot(lex-less)), shift
// lanes >= p up by one, lane p takes the candidate.
// Exactness: selection by (key,idx) lex = lax.top_k stable set; insert
// order irrelevant (final content = top-32 of union). Keys use R3's
// exact chain: d2 = (sa+sb) - 2*dot, key = fmaxf(d2,0).
// Radius pre-filter sqrtf(dk)<=0.8f is set-equivalent: the radius set
// is down-closed in key order, so top32(all) ∩ radius == top32(radius)
// (proof: if >=32 in-radius, the 32 global-nearest all have key <= the
// in-radius 32nd key, hence in-radius; else all in-radius points are
// among the global top-32). Sentinels (FLT_MAX, idx 0) fail the mask
// in mlp and idx 0 is a safe gather.
// =====================================================================
__global__ __launch_bounds__(256) void knn_kernel(const float4* __restrict__ pts4,
                                                  const int* __restrict__ fps_idx,
                                                  float* __restrict__ newxyz,
                                                  int* __restrict__ nn_idx,
                                                  float* __restrict__ nn_key) {
    const int lane = threadIdx.x & 63;
    const int g    = blockIdx.x * 4 + (threadIdx.x >> 6);   // centroid 0..8191
    const int b    = g >> 12;
    const float4* P = pts4 + (size_t)b * NPTS;

    const int far = fps_idx[g];
    const float4 C = P[far];
    if (lane == 0) {
        newxyz[g * 3 + 0] = C.x;
        newxyz[g * 3 + 1] = C.y;
        newxyz[g * 3 + 2] = C.z;
    }
    const float sa = C.w;

    float skey = FLT_MAX;   // lanes 0..31: sorted entries; lanes 32..63: inert
    int   sidx = 0;

    for (int it = 0; it < NPTS / 64; ++it) {
        const int j = it * 64 + lane;
        const float4 Q = P[j];
        const float dot = exadd(exadd(exmul(C.x, Q.x), exmul(C.y, Q.y)), exmul(C.z, Q.z));
        const float d2  = exsub(exadd(sa, Q.w), exadd(dot, dot));
        const float dk  = fmaxf(d2, 0.0f);
        // current 32nd-best (tau) from lane 31 — stale within the iteration is
        // fine: the insert itself recomputes the exact position.
        const float tk = __shfl(skey, 31);
        const int   ti = __shfl(sidx, 31);
        const bool pass = (sqrtf(dk) <= 0.8f) &&
                          ((dk < tk) || (dk == tk && j < ti));
        unsigned long long mask = __ballot(pass);
        while (mask) {
            const int src = __ffsll(mask) - 1;
            mask &= mask - 1;
            const float ck = __shfl(dk, src);
            const int   cj = it * 64 + src;
            const bool less = (skey < ck) || (skey == ck && sidx < cj);
            const int p = __popcll(__ballot(less));   // wave-uniform rank
            if (p < 32) {                              // wave-uniform branch
                const float upk = __shfl_up(skey, 1);
                const int   upi = __shfl_up(sidx, 1);
                if (lane < 32) {
                    if (lane == p)     { skey = ck;  sidx = cj; }
                    else if (lane > p) { skey = upk; sidx = upi; }
                }
            }
        }
    }
    if (lane < KGN) {
        nn_idx[(size_t)g * KGN + lane] = sidx;
        nn_key[(size_t)g * KGN + lane] = skey;
    }
}

// =====================================================================
// K3: shared MLP 3->32->32->64 (+BN affine +ReLU), radius mask via
// sqrtf(nn_key) <= 0.8 (R3 verbatim), max over 32 neighbors.
// waves_per_eu(4,4): h1+h2 = 64 live floats — same spill class as knn;
// raise budget to 128 (value-neutral).
// =====================================================================
__global__ __attribute__((amdgpu_waves_per_eu(4, 4)))
__launch_bounds__(256) void mlp_kernel(const float* __restrict__ xyz,
                                       const float* __restrict__ w1, const float* __restrict__ s1, const float* __restrict__ b1,
                                       const float* __restrict__ w2, const float* __restrict__ s2, const float* __restrict__ b2,
                                       const float* __restrict__ w3, const float* __restrict__ s3, const float* __restrict__ b3,
                                       const float* __restrict__ newxyz,
                                       const int* __restrict__ nn_idx,
                                       const float* __restrict__ nn_key,
                                       float* __restrict__ FLout) {
    __shared__ float W1[96], S1[32], B1[32];
    __shared__ float W2[1024], S2[32], B2[32];
    __shared__ float W3[2048], S3[64], B3[64];
    const int tid = threadIdx.x;
    for (int i = tid; i < 96; i += 256)   W1[i] = w1[i];
    for (int i = tid; i < 32; i += 256) { S1[i] = s1[i]; B1[i] = b1[i]; S2[i] = s2[i]; B2[i] = b2[i]; }
    for (int i = tid; i < 1024; i += 256) W2[i] = w2[i];
    for (int i = tid; i < 2048; i += 256) W3[i] = w3[i];
    for (int i = tid; i < 64; i += 256) { S3[i] = s3[i]; B3[i] = b3[i]; }
    __syncthreads();

    const int n  = tid & 31;
    const int g  = blockIdx.x * 8 + (tid >> 5);   // centroid 0..8191
    const int b  = g >> 12;
    const size_t base = (size_t)g * KGN + n;
    const int   nj = nn_idx[base];
    const float nk = nn_key[base];

    const float* X = xyz + (size_t)b * NPTS * 3;
    const float gx = X[nj * 3 + 0] - newxyz[g * 3 + 0];
    const float gy = X[nj * 3 + 1] - newxyz[g * 3 + 1];
    const float gz = X[nj * 3 + 2] - newxyz[g * 3 + 2];

    float h1[32];
#pragma unroll
    for (int o = 0; o < 32; ++o) {
        float a = gx * W1[o * 3 + 0] + gy * W1[o * 3 + 1] + gz * W1[o * 3 + 2];
        h1[o] = fmaxf(a * S1[o] + B1[o], 0.0f);
    }
    float h2[32];
#pragma unroll
    for (int o = 0; o < 32; ++o) {
        float a = 0.0f;
#pragma unroll
        for (int k = 0; k < 32; ++k) a += h1[k] * W2[o * 32 + k];
        h2[o] = fmaxf(a * S2[o] + B2[o], 0.0f);
    }
    const bool valid = (sqrtf(nk) <= 0.8f);   // exact mask (sentinel FLT_MAX -> false)

    for (int o = 0; o < 64; ++o) {
        float a = 0.0f;
#pragma unroll
        for (int k = 0; k < 32; ++k) a += h2[k] * W3[o * 32 + k];
        float v = fmaxf(a * S3[o] + B3[o], 0.0f);
        v = valid ? v : -INFINITY;
#pragma unroll
        for (int off = 1; off < 32; off <<= 1) v = fmaxf(v, __shfl_xor(v, off));
        if (n == (o & 31)) FLout[(size_t)g * CLN + o] = v;
    }
}

// =====================================================================
// K4: DAM fusion (R3 verbatim). Wave per centroid, lane = channel.
// LDS-transposed 64x64 weights for conflict-free per-lane reads.
// =====================================================================
__global__ __launch_bounds__(256) void fuse_kernel(const float* __restrict__ pts_cam,
                                                   const float* __restrict__ FIn,
                                                   const float* __restrict__ tw1, const float* __restrict__ tb1,
                                                   const float* __restrict__ tw2, const float* __restrict__ tb2,
                                                   const float* __restrict__ tw3, const float* __restrict__ tb3,
                                                   const float* __restrict__ gw_raw, const float* __restrict__ gb_raw,
                                                   const float* __restrict__ gw_img, const float* __restrict__ gb_img,
                                                   const float* __restrict__ gw_lid, const float* __restrict__ gb_lid,
                                                   const float* __restrict__ uw, const float* __restrict__ ub,
                                                   const float* __restrict__ vw, const float* __restrict__ vb,
                                                   const int* __restrict__ fps_idx,
                                                   const float* __restrict__ newxyz,
                                                   const float* __restrict__ FLin,
                                                   float* __restrict__ out) {
    __shared__ float WIm[4096], WLi[4096], WT2[4096];
    const int tid = threadIdx.x;
    for (int i = tid; i < 4096; i += 256) {
        int c = i >> 6, k = i & 63;          // weight[c][k] -> transposed [k][c]
        WIm[k * 64 + c] = gw_img[i];
        WLi[k * 64 + c] = gw_lid[i];
        WT2[k * 64 + c] = tw2[i];
    }
    __syncthreads();

    const int lane = tid & 63;
    const int g    = blockIdx.x * 4 + (tid >> 6);   // centroid 0..8191
    const int b    = g >> 12;
    const int m    = g & (MPTS - 1);
    const int far  = fps_idx[g];

    const float fi_in = FIn[((size_t)(b * CIN + lane)) * NPTS + far];
    const float fl_in = FLin[(size_t)g * CLN + lane];
    const float nx = newxyz[g * 3 + 0], ny = newxyz[g * 3 + 1], nz = newxyz[g * 3 + 2];

    float fr = fmaxf(nx * gw_raw[lane * 3 + 0] + ny * gw_raw[lane * 3 + 1] +
                     nz * gw_raw[lane * 3 + 2] + gb_raw[lane], 0.0f);

    float ai = gb_img[lane], al = gb_lid[lane];
#pragma unroll 8
    for (int k = 0; k < 64; ++k) {
        float vi = __shfl(fi_in, k);
        float vl = __shfl(fl_in, k);
        ai += vi * WIm[k * 64 + lane];
        al += vl * WLi[k * 64 + lane];
    }
    const float s = tanhf(fr + fmaxf(ai, 0.0f) + fmaxf(al, 0.0f));

    // AdaptiveThresholdNet on constant density
    const float dens = (float)(64.0 / (4.0 / 3.0 * 3.14159 * 1.0));
    float t1 = fmaxf(dens * tw1[lane] + tb1[lane], 0.0f);
    float a2 = tb2[lane];
#pragma unroll 8
    for (int k = 0; k < 64; ++k) a2 += __shfl(t1, k) * WT2[k * 64 + lane];
    float t2 = fmaxf(a2, 0.0f);
    float a3 = wave_sum64(t2 * tw3[lane]) + tb3[0];
    float thr = 20.0f + 40.0f * (1.0f / (1.0f + expf(-a3)));

    float aI = wave_sum64(s * uw[lane]) + ub[0];
    float aL = wave_sum64(s * vw[lane]) + vb[0];
    float wIv = 1.0f / (1.0f + expf(-aI));
    float wLv = 1.0f / (1.0f + expf(-aL));

    const float z = pts_cam[((size_t)b * NPTS + far) * 3 + 2];
    const bool near = (z <= thr);

    const size_t o1 = ((size_t)(b * 128 + lane)) * MPTS + m;
    out[o1]                       = near ? fl_in        : fi_in;
    out[o1 + (size_t)64 * MPTS]   = near ? fi_in * wIv  : fl_in * wLv;
}

// =====================================================================
extern "C" void kernel_launch(void* const* d_in, const int* in_sizes, int n_in,
                              void* d_out, int out_size, void* d_ws, size_t ws_size,
                              hipStream_t stream) {
    const float* xyz     = (const float*)d_in[0];
    const float* pts_cam = (const float*)d_in[1];
    const float* FI      = (const float*)d_in[2];
    const float* w1 = (const float*)d_in[3];
    const float* s1 = (const float*)d_in[4];
    const float* b1 = (const float*)d_in[5];
    const float* w2 = (const float*)d_in[6];
    const float* s2 = (const float*)d_in[7];
    const float* b2 = (const float*)d_in[8];
    const float* w3 = (const float*)d_in[9];
    const float* s3 = (const float*)d_in[10];
    const float* b3 = (const float*)d_in[11];
    const float* tw1 = (const float*)d_in[12];
    const float* tb1 = (const float*)d_in[13];
    const float* tw2 = (const float*)d_in[14];
    const float* tb2 = (const float*)d_in[15];
    const float* tw3 = (const float*)d_in[16];
    const float* tb3 = (const float*)d_in[17];
    const float* gw_raw = (const float*)d_in[18];
    const float* gb_raw = (const float*)d_in[19];
    const float* gw_img = (const float*)d_in[20];
    const float* gb_img = (const float*)d_in[21];
    const float* gw_lid = (const float*)d_in[22];
    const float* gb_lid = (const float*)d_in[23];
    const float* uw = (const float*)d_in[24];
    const float* ub = (const float*)d_in[25];
    const float* vw = (const float*)d_in[26];
    const float* vb = (const float*)d_in[27];
    float* out = (float*)d_out;

    // workspace layout (bytes) — total 4,325,376.
    // pts4 is dead after knn; FL (written by mlp, later) aliases its region.
    char* ws = (char*)d_ws;
    int*    ws_idx    = (int*)   (ws + 0);         // 8192 ints    (32 KB)
    float*  ws_newxyz = (float*) (ws + 32768);     // 24576 f      (96 KB)  -> 131072
    float4* ws_pts4   = (float4*)(ws + 131072);    // 32768 float4 (512 KB) -> 655360 [dead after knn]
    float*  ws_FL     = (float*) (ws + 131072);    // 524288 f     (2 MB)   -> 2228224 [aliases pts4]
    int*    ws_nnidx  = (int*)   (ws + 2228224);   // 262144 ints  (1 MB)   -> 3276800
    float*  ws_nnkey  = (float*) (ws + 3276800);   // 262144 f     (1 MB)   -> 4325376
    (void)ws_size; (void)in_sizes; (void)n_in; (void)out_size;

    prep_kernel<<<(BN * NPTS) / 256, 256, 0, stream>>>(xyz, ws_pts4);
    fps_kernel<<<BN, 512, 0, stream>>>(ws_pts4, ws_idx);
    knn_kernel<<<2048, 256, 0, stream>>>(ws_pts4, ws_idx, ws_newxyz, ws_nnidx, ws_nnkey);
    mlp_kernel<<<1024, 256, 0, stream>>>(xyz, w1, s1, b1, w2, s2, b2, w3, s3, b3,
                                         ws_newxyz, ws_nnidx, ws_nnkey, ws_FL);
    fuse_kernel<<<2048, 256, 0, stream>>>(pts_cam, FI, tw1, tb1, tw2, tb2, tw3, tb3,
                                          gw_raw, gb_raw, gw_img, gb_img, gw_lid, gb_lid,
                                          uw, ub, vw, vb, ws_idx, ws_newxyz, ws_FL, out);
}

// Round 6
// 7436.810 us; speedup vs baseline: 1.4102x; 1.0134x over previous
//
#include <hip/hip_runtime.h>
#include <math.h>
#include <float.h>

#define BN   2
#define NPTS 16384
#define MPTS 4096
#define KGN  32
#define CIN  64
#define CLN  64

// ---------- exact fp32 helpers (no FMA contraction; must match np fp32) ----------
__device__ __forceinline__ float exadd(float a, float b) {
#pragma clang fp contract(off)
    float r = a + b; return r;
}
__device__ __forceinline__ float exsub(float a, float b) {
#pragma clang fp contract(off)
    float r = a - b; return r;
}
__device__ __forceinline__ float exmul(float a, float b) {
#pragma clang fp contract(off)
    float r = a * b; return r;
}

__device__ __forceinline__ float wave_sum64(float v) {
#pragma unroll
    for (int off = 1; off < 64; off <<= 1) v += __shfl_xor(v, off);
    return v;
}

// =====================================================================
// K0: pack points as float4(x, y, z, ||p||^2) once. sb order matches
// jnp.sum(b*b,-1): ((x*x + y*y) + z*z), contract off. Values verbatim.
// =====================================================================
__global__ __launch_bounds__(256) void prep_kernel(const float* __restrict__ xyz,
                                                   float4* __restrict__ pts4) {
    const int i = blockIdx.x * 256 + threadIdx.x;   // 0 .. BN*NPTS-1
    const float x = xyz[3 * i + 0];
    const float y = xyz[3 * i + 1];
    const float z = xyz[3 * i + 2];
    const float sb = exadd(exadd(exmul(x, x), exmul(y, y)), exmul(z, z));
    pts4[i] = make_float4(x, y, z, sb);
}

// =====================================================================
// K1: FPS — R8: R1's PROVEN plumbing (best measured 6726us), with the
// asm pins REMOVED.
// Diagnosis history: R1-R5 all showed VGPR_Count 52-84 and ~263MB
// FETCH_SIZE regardless of occupancy attributes. The
// `asm volatile("" : "+v"(px[i]))` pins take array elements as asm
// operands inside a not-yet-unrolled loop, which blocks SROA from
// promoting px/py/pz/dist to registers -> the arrays live in SCRATCH
// and every access is a scratch load/store (the real per-iteration
// cost; rule #20 failure mode). Removing the pins + static unrolled
// indices + __launch_bounds__(1024,4) (cap 128 VGPR; working set
// ~95) lets SROA promote and the allocator keep everything register-
// resident with no pressure.
// Value chain is verbatim-equivalent to the passing kernel:
//   d = (dx*dx + dy*dy) + dz*dz  (fp32, no contraction),
//   dist = fminf(dist, d), init 1e10, start index 0,
//   argmax tie-break = first occurrence (smallest global index).
// Ownership: thread t owns gidx = t*16 + i (contiguous) -> within
// thread, descending scan gives smallest matching gidx; across
// threads, atomicMin over explicit global indices. bm is bit-exact
// (fmaxf tree of exact values returns one of them; dists >= +0.0,
// no NaN), so dist==bm matches at least one thread.
// swidx ping-pong reset ordering (R1-proven): reset of slot (m+1)&1
// sits between B1(m) and B2(m); its readers finished before B1(m);
// its next writers start after B1(m+1) > B2(m) > reset. No race.
// =====================================================================
__global__ __launch_bounds__(1024, 4) void fps_kernel(const float4* __restrict__ P4,
                                                      int* __restrict__ out_idx) {
    const int b = blockIdx.x;
    const int t = threadIdx.x;
    const float4* P = P4 + (size_t)b * NPTS;

    float px[16], py[16], pz[16], dist[16];
#pragma unroll
    for (int i = 0; i < 16; ++i) {
        float4 a = P[t * 16 + i];
        px[i] = a.x;
        py[i] = a.y;
        pz[i] = a.z;
        dist[i] = 1e10f;
    }

    __shared__ float smax[16];
    __shared__ int   swidx[2];

    if (t == 0) { swidx[0] = 0x7FFFFFFF; swidx[1] = 0x7FFFFFFF; }
    __syncthreads();

    int cidx = 0;   // current centroid index == out_idx[m] (reference: far starts at 0)

    for (int m = 0; m < MPTS; ++m) {
        if (t == 0) out_idx[b * MPTS + m] = cidx;   // fire-and-forget store

        // scalar broadcast load of the centroid (uniform address -> s_load)
        const int ci = __builtin_amdgcn_readfirstlane(cidx);
        const float4 C = P[ci];
        const float cx = C.x, cy = C.y, cz = C.z;

        float lmax = -1.0f;
#pragma unroll
        for (int i = 0; i < 16; ++i) {
            float dx = exsub(px[i], cx);
            float dy = exsub(py[i], cy);
            float dz = exsub(pz[i], cz);
            float d  = exadd(exadd(exmul(dx, dx), exmul(dy, dy)), exmul(dz, dz));
            float nd = fminf(dist[i], d);
            dist[i] = nd;
            lmax = fmaxf(lmax, nd);
        }

        // wave-level f32 max
        float wmax = lmax;
#pragma unroll
        for (int off = 1; off < 64; off <<= 1) wmax = fmaxf(wmax, __shfl_xor(wmax, off));
        if ((t & 63) == 0) smax[t >> 6] = wmax;

        __syncthreads();                               // B1

        // reset the slot used NEXT iteration (ordering: see header proof)
        if (t == 0) swidx[(m + 1) & 1] = 0x7FFFFFFF;

        // block max — replicated parallel reduce, every thread ends with bm
        float bm = smax[t & 15];
#pragma unroll
        for (int off = 1; off < 16; off <<= 1) bm = fmaxf(bm, __shfl_xor(bm, off));

        // candidates publish min global index (exact first-index tie-break)
        if (lmax == bm) {
            int sel = 0;
#pragma unroll
            for (int i = 15; i >= 0; --i) {            // descending: final hit = smallest i
                if (dist[i] == bm) sel = i;
            }
            atomicMin(&swidx[m & 1], t * 16 + sel);
        }

        __syncthreads();                               // B2
        cidx = swidx[m & 1];
    }
}

// =====================================================================
// K2: exact 32-NN, wave per centroid, NO per-lane arrays (R3 spilled
// its key[32]/nid[32] to scratch: 18.9 GB FETCH / 12.6 GB WRITE).
// Wave-wide sorted top-32 lives in ONE (key,idx) register pair per
// lane (lanes 0..31, ascending (key,idx) lex). Candidates found via
// ballot; each inserted exactly: p = popc(ballot(lex-less)), shift
// lanes >= p up by one, lane p takes the candidate.
// Exactness: selection by (key,idx) lex = lax.top_k stable set; insert
// order irrelevant (final content = top-32 of union). Keys use R3's
// exact chain: d2 = (sa+sb) - 2*dot, key = fmaxf(d2,0).
// Radius pre-filter sqrtf(dk)<=0.8f is set-equivalent: the radius set
// is down-closed in key order, so top32(all) ∩ radius == top32(radius)
// (proof: if >=32 in-radius, the 32 global-nearest all have key <= the
// in-radius 32nd key, hence in-radius; else all in-radius points are
// among the global top-32). Sentinels (FLT_MAX, idx 0) fail the mask
// in mlp and idx 0 is a safe gather.
// =====================================================================
__global__ __launch_bounds__(256) void knn_kernel(const float4* __restrict__ pts4,
                                                  const int* __restrict__ fps_idx,
                                                  float* __restrict__ newxyz,
                                                  int* __restrict__ nn_idx,
                                                  float* __restrict__ nn_key) {
    const int lane = threadIdx.x & 63;
    const int g    = blockIdx.x * 4 + (threadIdx.x >> 6);   // centroid 0..8191
    const int b    = g >> 12;
    const float4* P = pts4 + (size_t)b * NPTS;

    const int far = fps_idx[g];
    const float4 C = P[far];
    if (lane == 0) {
        newxyz[g * 3 + 0] = C.x;
        newxyz[g * 3 + 1] = C.y;
        newxyz[g * 3 + 2] = C.z;
    }
    const float sa = C.w;

    float skey = FLT_MAX;   // lanes 0..31: sorted entries; lanes 32..63: inert
    int   sidx = 0;

    for (int it = 0; it < NPTS / 64; ++it) {
        const int j = it * 64 + lane;
        const float4 Q = P[j];
        const float dot = exadd(exadd(exmul(C.x, Q.x), exmul(C.y, Q.y)), exmul(C.z, Q.z));
        const float d2  = exsub(exadd(sa, Q.w), exadd(dot, dot));
        const float dk  = fmaxf(d2, 0.0f);
        // current 32nd-best (tau) from lane 31 — stale within the iteration is
        // fine: the insert itself recomputes the exact position.
        const float tk = __shfl(skey, 31);
        const int   ti = __shfl(sidx, 31);
        const bool pass = (sqrtf(dk) <= 0.8f) &&
                          ((dk < tk) || (dk == tk && j < ti));
        unsigned long long mask = __ballot(pass);
        while (mask) {
            const int src = __ffsll(mask) - 1;
            mask &= mask - 1;
            const float ck = __shfl(dk, src);
            const int   cj = it * 64 + src;
            const bool less = (skey < ck) || (skey == ck && sidx < cj);
            const int p = __popcll(__ballot(less));   // wave-uniform rank
            if (p < 32) {                              // wave-uniform branch
                const float upk = __shfl_up(skey, 1);
                const int   upi = __shfl_up(sidx, 1);
                if (lane < 32) {
                    if (lane == p)     { skey = ck;  sidx = cj; }
                    else if (lane > p) { skey = upk; sidx = upi; }
                }
            }
        }
    }
    if (lane < KGN) {
        nn_idx[(size_t)g * KGN + lane] = sidx;
        nn_key[(size_t)g * KGN + lane] = skey;
    }
}

// =====================================================================
// K3: shared MLP 3->32->32->64 (+BN affine +ReLU), radius mask via
// sqrtf(nn_key) <= 0.8 (R3 verbatim), max over 32 neighbors.
// waves_per_eu(4,4): h1+h2 = 64 live floats — same spill class as knn;
// raise budget to 128 (value-neutral).
// =====================================================================
__global__ __attribute__((amdgpu_waves_per_eu(4, 4)))
__launch_bounds__(256) void mlp_kernel(const float* __restrict__ xyz,
                                       const float* __restrict__ w1, const float* __restrict__ s1, const float* __restrict__ b1,
                                       const float* __restrict__ w2, const float* __restrict__ s2, const float* __restrict__ b2,
                                       const float* __restrict__ w3, const float* __restrict__ s3, const float* __restrict__ b3,
                                       const float* __restrict__ newxyz,
                                       const int* __restrict__ nn_idx,
                                       const float* __restrict__ nn_key,
                                       float* __restrict__ FLout) {
    __shared__ float W1[96], S1[32], B1[32];
    __shared__ float W2[1024], S2[32], B2[32];
    __shared__ float W3[2048], S3[64], B3[64];
    const int tid = threadIdx.x;
    for (int i = tid; i < 96; i += 256)   W1[i] = w1[i];
    for (int i = tid; i < 32; i += 256) { S1[i] = s1[i]; B1[i] = b1[i]; S2[i] = s2[i]; B2[i] = b2[i]; }
    for (int i = tid; i < 1024; i += 256) W2[i] = w2[i];
    for (int i = tid; i < 2048; i += 256) W3[i] = w3[i];
    for (int i = tid; i < 64; i += 256) { S3[i] = s3[i]; B3[i] = b3[i]; }
    __syncthreads();

    const int n  = tid & 31;
    const int g  = blockIdx.x * 8 + (tid >> 5);   // centroid 0..8191
    const int b  = g >> 12;
    const size_t base = (size_t)g * KGN + n;
    const int   nj = nn_idx[base];
    const float nk = nn_key[base];

    const float* X = xyz + (size_t)b * NPTS * 3;
    const float gx = X[nj * 3 + 0] - newxyz[g * 3 + 0];
    const float gy = X[nj * 3 + 1] - newxyz[g * 3 + 1];
    const float gz = X[nj * 3 + 2] - newxyz[g * 3 + 2];

    float h1[32];
#pragma unroll
    for (int o = 0; o < 32; ++o) {
        float a = gx * W1[o * 3 + 0] + gy * W1[o * 3 + 1] + gz * W1[o * 3 + 2];
        h1[o] = fmaxf(a * S1[o] + B1[o], 0.0f);
    }
    float h2[32];
#pragma unroll
    for (int o = 0; o < 32; ++o) {
        float a = 0.0f;
#pragma unroll
        for (int k = 0; k < 32; ++k) a += h1[k] * W2[o * 32 + k];
        h2[o] = fmaxf(a * S2[o] + B2[o], 0.0f);
    }
    const bool valid = (sqrtf(nk) <= 0.8f);   // exact mask (sentinel FLT_MAX -> false)

    for (int o = 0; o < 64; ++o) {
        float a = 0.0f;
#pragma unroll
        for (int k = 0; k < 32; ++k) a += h2[k] * W3[o * 32 + k];
        float v = fmaxf(a * S3[o] + B3[o], 0.0f);
        v = valid ? v : -INFINITY;
#pragma unroll
        for (int off = 1; off < 32; off <<= 1) v = fmaxf(v, __shfl_xor(v, off));
        if (n == (o & 31)) FLout[(size_t)g * CLN + o] = v;
    }
}

// =====================================================================
// K4: DAM fusion (R3 verbatim). Wave per centroid, lane = channel.
// LDS-transposed 64x64 weights for conflict-free per-lane reads.
// =====================================================================
__global__ __launch_bounds__(256) void fuse_kernel(const float* __restrict__ pts_cam,
                                                   const float* __restrict__ FIn,
                                                   const float* __restrict__ tw1, const float* __restrict__ tb1,
                                                   const float* __restrict__ tw2, const float* __restrict__ tb2,
                                                   const float* __restrict__ tw3, const float* __restrict__ tb3,
                                                   const float* __restrict__ gw_raw, const float* __restrict__ gb_raw,
                                                   const float* __restrict__ gw_img, const float* __restrict__ gb_img,
                                                   const float* __restrict__ gw_lid, const float* __restrict__ gb_lid,
                                                   const float* __restrict__ uw, const float* __restrict__ ub,
                                                   const float* __restrict__ vw, const float* __restrict__ vb,
                                                   const int* __restrict__ fps_idx,
                                                   const float* __restrict__ newxyz,
                                                   const float* __restrict__ FLin,
                                                   float* __restrict__ out) {
    __shared__ float WIm[4096], WLi[4096], WT2[4096];
    const int tid = threadIdx.x;
    for (int i = tid; i < 4096; i += 256) {
        int c = i >> 6, k = i & 63;          // weight[c][k] -> transposed [k][c]
        WIm[k * 64 + c] = gw_img[i];
        WLi[k * 64 + c] = gw_lid[i];
        WT2[k * 64 + c] = tw2[i];
    }
    __syncthreads();

    const int lane = tid & 63;
    const int g    = blockIdx.x * 4 + (tid >> 6);   // centroid 0..8191
    const int b    = g >> 12;
    const int m    = g & (MPTS - 1);
    const int far  = fps_idx[g];

    const float fi_in = FIn[((size_t)(b * CIN + lane)) * NPTS + far];
    const float fl_in = FLin[(size_t)g * CLN + lane];
    const float nx = newxyz[g * 3 + 0], ny = newxyz[g * 3 + 1], nz = newxyz[g * 3 + 2];

    float fr = fmaxf(nx * gw_raw[lane * 3 + 0] + ny * gw_raw[lane * 3 + 1] +
                     nz * gw_raw[lane * 3 + 2] + gb_raw[lane], 0.0f);

    float ai = gb_img[lane], al = gb_lid[lane];
#pragma unroll 8
    for (int k = 0; k < 64; ++k) {
        float vi = __shfl(fi_in, k);
        float vl = __shfl(fl_in, k);
        ai += vi * WIm[k * 64 + lane];
        al += vl * WLi[k * 64 + lane];
    }
    const float s = tanhf(fr + fmaxf(ai, 0.0f) + fmaxf(al, 0.0f));

    // AdaptiveThresholdNet on constant density
    const float dens = (float)(64.0 / (4.0 / 3.0 * 3.14159 * 1.0));
    float t1 = fmaxf(dens * tw1[lane] + tb1[lane], 0.0f);
    float a2 = tb2[lane];
#pragma unroll 8
    for (int k = 0; k < 64; ++k) a2 += __shfl(t1, k) * WT2[k * 64 + lane];
    float t2 = fmaxf(a2, 0.0f);
    float a3 = wave_sum64(t2 * tw3[lane]) + tb3[0];
    float thr = 20.0f + 40.0f * (1.0f / (1.0f + expf(-a3)));

    float aI = wave_sum64(s * uw[lane]) + ub[0];
    float aL = wave_sum64(s * vw[lane]) + vb[0];
    float wIv = 1.0f / (1.0f + expf(-aI));
    float wLv = 1.0f / (1.0f + expf(-aL));

    const float z = pts_cam[((size_t)b * NPTS + far) * 3 + 2];
    const bool near = (z <= thr);

    const size_t o1 = ((size_t)(b * 128 + lane)) * MPTS + m;
    out[o1]                       = near ? fl_in        : fi_in;
    out[o1 + (size_t)64 * MPTS]   = near ? fi_in * wIv  : fl_in * wLv;
}

// =====================================================================
extern "C" void kernel_launch(void* const* d_in, const int* in_sizes, int n_in,
                              void* d_out, int out_size, void* d_ws, size_t ws_size,
                              hipStream_t stream) {
    const float* xyz     = (const float*)d_in[0];
    const float* pts_cam = (const float*)d_in[1];
    const float* FI      = (const float*)d_in[2];
    const float* w1 = (const float*)d_in[3];
    const float* s1 = (const float*)d_in[4];
    const float* b1 = (const float*)d_in[5];
    const float* w2 = (const float*)d_in[6];
    const float* s2 = (const float*)d_in[7];
    const float* b2 = (const float*)d_in[8];
    const float* w3 = (const float*)d_in[9];
    const float* s3 = (const float*)d_in[10];
    const float* b3 = (const float*)d_in[11];
    const float* tw1 = (const float*)d_in[12];
    const float* tb1 = (const float*)d_in[13];
    const float* tw2 = (const float*)d_in[14];
    const float* tb2 = (const float*)d_in[15];
    const float* tw3 = (const float*)d_in[16];
    const float* tb3 = (const float*)d_in[17];
    const float* gw_raw = (const float*)d_in[18];
    const float* gb_raw = (const float*)d_in[19];
    const float* gw_img = (const float*)d_in[20];
    const float* gb_img = (const float*)d_in[21];
    const float* gw_lid = (const float*)d_in[22];
    const float* gb_lid = (const float*)d_in[23];
    const float* uw = (const float*)d_in[24];
    const float* ub = (const float*)d_in[25];
    const float* vw = (const float*)d_in[26];
    const float* vb = (const float*)d_in[27];
    float* out = (float*)d_out;

    // workspace layout (bytes) — total 4,325,376.
    // pts4 is dead after knn; FL (written by mlp, later) aliases its region.
    char* ws = (char*)d_ws;
    int*    ws_idx    = (int*)   (ws + 0);         // 8192 ints    (32 KB)
    float*  ws_newxyz = (float*) (ws + 32768);     // 24576 f      (96 KB)  -> 131072
    float4* ws_pts4   = (float4*)(ws + 131072);    // 32768 float4 (512 KB) -> 655360 [dead after knn]
    float*  ws_FL     = (float*) (ws + 131072);    // 524288 f     (2 MB)   -> 2228224 [aliases pts4]
    int*    ws_nnidx  = (int*)   (ws + 2228224);   // 262144 ints  (1 MB)   -> 3276800
    float*  ws_nnkey  = (float*) (ws + 3276800);   // 262144 f     (1 MB)   -> 4325376
    (void)ws_size; (void)in_sizes; (void)n_in; (void)out_size;

    prep_kernel<<<(BN * NPTS) / 256, 256, 0, stream>>>(xyz, ws_pts4);
    fps_kernel<<<BN, 1024, 0, stream>>>(ws_pts4, ws_idx);
    knn_kernel<<<2048, 256, 0, stream>>>(ws_pts4, ws_idx, ws_newxyz, ws_nnidx, ws_nnkey);
    mlp_kernel<<<1024, 256, 0, stream>>>(xyz, w1, s1, b1, w2, s2, b2, w3, s3, b3,
                                         ws_newxyz, ws_nnidx, ws_nnkey, ws_FL);
    fuse_kernel<<<2048, 256, 0, stream>>>(pts_cam, FI, tw1, tb1, tw2, tb2, tw3, tb3,
                                          gw_raw, gb_raw, gw_img, gb_img, gw_lid, gb_lid,
                                          uw, ub, vw, vb, ws_idx, ws_newxyz, ws_FL, out);
}

// Round 7
// 6377.256 us; speedup vs baseline: 1.6445x; 1.1661x over previous
//
#include <hip/hip_runtime.h>
#include <math.h>
#include <float.h>

#define BN   2
#define NPTS 16384
#define MPTS 4096
#define KGN  32
#define CIN  64
#define CLN  64

// ---------- exact fp32 helpers (no FMA contraction; must match np fp32) ----------
__device__ __forceinline__ float exadd(float a, float b) {
#pragma clang fp contract(off)
    float r = a + b; return r;
}
__device__ __forceinline__ float exsub(float a, float b) {
#pragma clang fp contract(off)
    float r = a - b; return r;
}
__device__ __forceinline__ float exmul(float a, float b) {
#pragma clang fp contract(off)
    float r = a * b; return r;
}

__device__ __forceinline__ float wave_sum64(float v) {
#pragma unroll
    for (int off = 1; off < 64; off <<= 1) v += __shfl_xor(v, off);
    return v;
}

// =====================================================================
// K0: pack points as float4(x, y, z, ||p||^2) once. sb order matches
// jnp.sum(b*b,-1): ((x*x + y*y) + z*z), contract off. Values verbatim.
// =====================================================================
__global__ __launch_bounds__(256) void prep_kernel(const float* __restrict__ xyz,
                                                   float4* __restrict__ pts4) {
    const int i = blockIdx.x * 256 + threadIdx.x;   // 0 .. BN*NPTS-1
    const float x = xyz[3 * i + 0];
    const float y = xyz[3 * i + 1];
    const float z = xyz[3 * i + 2];
    const float sb = exadd(exadd(exmul(x, x), exmul(y, y)), exmul(z, z));
    pts4[i] = make_float4(x, y, z, sb);
}

// =====================================================================
// K1: FPS — R9: REGISTER-RESIDENT point set via named scalars + pins.
// Diagnosis across R1-R6 (counters): VGPR_Count 48-84 with a 64-128
// float/thread working set => point coords were NEVER in registers.
//   * with array-element asm pins (R1/R5): SROA blocked -> arrays in
//     SCRATCH (re-read every iter).
//   * without pins (R6, VGPR=48): backend REMATERIALIZES the read-only
//     global loads inside the loop (P4 is const __restrict__).
// Both states re-read ~256 B/thread/iter from L2 => ~4000 cyc/iter,
// L2-BW-bound on one CU (263 MB FETCH = miss tail of that stream).
// Fix: 64 NAMED SCALARS (no alloca -> nothing for SROA to miss) each
// pinned ONCE outside the loop via asm volatile "+v" — the defining
// instruction becomes a volatile asm, which the backend cannot
// duplicate/rematerialize, so the values must stay in VGPRs.
// __launch_bounds__(1024,4): 16-wave block, 1 block/CU, 128-VGPR cap;
// need ~90 -> fits without pressure.
// Value chain is verbatim-equivalent to the passing kernel:
//   d = (dx*dx + dy*dy) + dz*dz  (fp32, no contraction),
//   dist = fminf(dist, d), init 1e10, start index 0,
//   argmax tie-break = first occurrence (smallest global index).
// Ownership: thread t owns gidx = t*16 + i (contiguous). Tie-break:
// within thread the scan checks i=15 first and i=0 LAST (last
// assignment wins) => smallest matching i; across threads atomicMin
// over explicit global indices. bm is bit-exact (fmaxf tree of exact
// values returns one of them; dists >= +0.0, no NaN).
// swidx ping-pong reset ordering (R1-proven): reset of slot (m+1)&1
// sits between B1(m) and B2(m); its readers finished before B1(m);
// its next writers start after B1(m+1) > B2(m) > reset. No race.
// =====================================================================
__global__ __launch_bounds__(1024, 4) void fps_kernel(const float4* __restrict__ P4,
                                                      int* __restrict__ out_idx) {
    const int b = blockIdx.x;
    const int t = threadIdx.x;
    const float4* P = P4 + (size_t)b * NPTS;

    // ---- load 16 points into NAMED scalars, then pin each once ----
#define FPS_LOAD(i) float4 a##i = P[t * 16 + i];
    FPS_LOAD(0)  FPS_LOAD(1)  FPS_LOAD(2)  FPS_LOAD(3)
    FPS_LOAD(4)  FPS_LOAD(5)  FPS_LOAD(6)  FPS_LOAD(7)
    FPS_LOAD(8)  FPS_LOAD(9)  FPS_LOAD(10) FPS_LOAD(11)
    FPS_LOAD(12) FPS_LOAD(13) FPS_LOAD(14) FPS_LOAD(15)
#undef FPS_LOAD

#define FPS_PIN(i) \
    float px##i = a##i.x, py##i = a##i.y, pz##i = a##i.z, dd##i = 1e10f; \
    asm volatile("" : "+v"(px##i), "+v"(py##i), "+v"(pz##i));
    FPS_PIN(0)  FPS_PIN(1)  FPS_PIN(2)  FPS_PIN(3)
    FPS_PIN(4)  FPS_PIN(5)  FPS_PIN(6)  FPS_PIN(7)
    FPS_PIN(8)  FPS_PIN(9)  FPS_PIN(10) FPS_PIN(11)
    FPS_PIN(12) FPS_PIN(13) FPS_PIN(14) FPS_PIN(15)
#undef FPS_PIN

    __shared__ float smax[16];
    __shared__ int   swidx[2];

    if (t == 0) { swidx[0] = 0x7FFFFFFF; swidx[1] = 0x7FFFFFFF; }
    __syncthreads();

    int cidx = 0;   // current centroid index == out_idx[m] (reference: far starts at 0)

    for (int m = 0; m < MPTS; ++m) {
        if (t == 0) out_idx[b * MPTS + m] = cidx;   // fire-and-forget store

        // scalar broadcast load of the centroid (uniform address -> s_load)
        const int ci = __builtin_amdgcn_readfirstlane(cidx);
        const float4 C = P[ci];
        const float cx = C.x, cy = C.y, cz = C.z;

        float lmax = -1.0f;
#define FPS_UPD(i) { \
        float dx = exsub(px##i, cx); \
        float dy = exsub(py##i, cy); \
        float dz = exsub(pz##i, cz); \
        float d  = exadd(exadd(exmul(dx, dx), exmul(dy, dy)), exmul(dz, dz)); \
        dd##i = fminf(dd##i, d); \
        lmax = fmaxf(lmax, dd##i); }
        FPS_UPD(0)  FPS_UPD(1)  FPS_UPD(2)  FPS_UPD(3)
        FPS_UPD(4)  FPS_UPD(5)  FPS_UPD(6)  FPS_UPD(7)
        FPS_UPD(8)  FPS_UPD(9)  FPS_UPD(10) FPS_UPD(11)
        FPS_UPD(12) FPS_UPD(13) FPS_UPD(14) FPS_UPD(15)
#undef FPS_UPD

        // wave-level f32 max
        float wmax = lmax;
#pragma unroll
        for (int off = 1; off < 64; off <<= 1) wmax = fmaxf(wmax, __shfl_xor(wmax, off));
        if ((t & 63) == 0) smax[t >> 6] = wmax;

        __syncthreads();                               // B1

        // reset the slot used NEXT iteration (ordering: see header proof)
        if (t == 0) swidx[(m + 1) & 1] = 0x7FFFFFFF;

        // block max — replicated parallel reduce, every thread ends with bm
        float bm = smax[t & 15];
#pragma unroll
        for (int off = 1; off < 16; off <<= 1) bm = fmaxf(bm, __shfl_xor(bm, off));

        // candidates publish min global index (exact first-index tie-break)
        if (lmax == bm) {
            int sel = 0;
            // i=15 checked FIRST, i=0 LAST -> last assignment wins -> smallest i
#define FPS_SCAN(i) if (dd##i == bm) sel = i;
            FPS_SCAN(15) FPS_SCAN(14) FPS_SCAN(13) FPS_SCAN(12)
            FPS_SCAN(11) FPS_SCAN(10) FPS_SCAN(9)  FPS_SCAN(8)
            FPS_SCAN(7)  FPS_SCAN(6)  FPS_SCAN(5)  FPS_SCAN(4)
            FPS_SCAN(3)  FPS_SCAN(2)  FPS_SCAN(1)  FPS_SCAN(0)
#undef FPS_SCAN
            atomicMin(&swidx[m & 1], t * 16 + sel);
        }

        __syncthreads();                               // B2
        cidx = swidx[m & 1];
    }
}

// =====================================================================
// K2: exact 32-NN, wave per centroid, NO per-lane arrays (R3 spilled
// its key[32]/nid[32] to scratch: 18.9 GB FETCH / 12.6 GB WRITE).
// Wave-wide sorted top-32 lives in ONE (key,idx) register pair per
// lane (lanes 0..31, ascending (key,idx) lex). Candidates found via
// ballot; each inserted exactly: p = popc(ballot(lex-less)), shift
// lanes >= p up by one, lane p takes the candidate.
// Exactness: selection by (key,idx) lex = lax.top_k stable set; insert
// order irrelevant (final content = top-32 of union). Keys use R3's
// exact chain: d2 = (sa+sb) - 2*dot, key = fmaxf(d2,0).
// Radius pre-filter sqrtf(dk)<=0.8f is set-equivalent: the radius set
// is down-closed in key order, so top32(all) ∩ radius == top32(radius)
// (proof: if >=32 in-radius, the 32 global-nearest all have key <= the
// in-radius 32nd key, hence in-radius; else all in-radius points are
// among the global top-32). Sentinels (FLT_MAX, idx 0) fail the mask
// in mlp and idx 0 is a safe gather.
// =====================================================================
__global__ __launch_bounds__(256) void knn_kernel(const float4* __restrict__ pts4,
                                                  const int* __restrict__ fps_idx,
                                                  float* __restrict__ newxyz,
                                                  int* __restrict__ nn_idx,
                                                  float* __restrict__ nn_key) {
    const int lane = threadIdx.x & 63;
    const int g    = blockIdx.x * 4 + (threadIdx.x >> 6);   // centroid 0..8191
    const int b    = g >> 12;
    const float4* P = pts4 + (size_t)b * NPTS;

    const int far = fps_idx[g];
    const float4 C = P[far];
    if (lane == 0) {
        newxyz[g * 3 + 0] = C.x;
        newxyz[g * 3 + 1] = C.y;
        newxyz[g * 3 + 2] = C.z;
    }
    const float sa = C.w;

    float skey = FLT_MAX;   // lanes 0..31: sorted entries; lanes 32..63: inert
    int   sidx = 0;

    for (int it = 0; it < NPTS / 64; ++it) {
        const int j = it * 64 + lane;
        const float4 Q = P[j];
        const float dot = exadd(exadd(exmul(C.x, Q.x), exmul(C.y, Q.y)), exmul(C.z, Q.z));
        const float d2  = exsub(exadd(sa, Q.w), exadd(dot, dot));
        const float dk  = fmaxf(d2, 0.0f);
        // current 32nd-best (tau) from lane 31 — stale within the iteration is
        // fine: the insert itself recomputes the exact position.
        const float tk = __shfl(skey, 31);
        const int   ti = __shfl(sidx, 31);
        const bool pass = (sqrtf(dk) <= 0.8f) &&
                          ((dk < tk) || (dk == tk && j < ti));
        unsigned long long mask = __ballot(pass);
        while (mask) {
            const int src = __ffsll(mask) - 1;
            mask &= mask - 1;
            const float ck = __shfl(dk, src);
            const int   cj = it * 64 + src;
            const bool less = (skey < ck) || (skey == ck && sidx < cj);
            const int p = __popcll(__ballot(less));   // wave-uniform rank
            if (p < 32) {                              // wave-uniform branch
                const float upk = __shfl_up(skey, 1);
                const int   upi = __shfl_up(sidx, 1);
                if (lane < 32) {
                    if (lane == p)     { skey = ck;  sidx = cj; }
                    else if (lane > p) { skey = upk; sidx = upi; }
                }
            }
        }
    }
    if (lane < KGN) {
        nn_idx[(size_t)g * KGN + lane] = sidx;
        nn_key[(size_t)g * KGN + lane] = skey;
    }
}

// =====================================================================
// K3: shared MLP 3->32->32->64 (+BN affine +ReLU), radius mask via
// sqrtf(nn_key) <= 0.8 (R3 verbatim), max over 32 neighbors.
// waves_per_eu(4,4): h1+h2 = 64 live floats — same spill class as knn;
// raise budget to 128 (value-neutral).
// =====================================================================
__global__ __attribute__((amdgpu_waves_per_eu(4, 4)))
__launch_bounds__(256) void mlp_kernel(const float* __restrict__ xyz,
                                       const float* __restrict__ w1, const float* __restrict__ s1, const float* __restrict__ b1,
                                       const float* __restrict__ w2, const float* __restrict__ s2, const float* __restrict__ b2,
                                       const float* __restrict__ w3, const float* __restrict__ s3, const float* __restrict__ b3,
                                       const float* __restrict__ newxyz,
                                       const int* __restrict__ nn_idx,
                                       const float* __restrict__ nn_key,
                                       float* __restrict__ FLout) {
    __shared__ float W1[96], S1[32], B1[32];
    __shared__ float W2[1024], S2[32], B2[32];
    __shared__ float W3[2048], S3[64], B3[64];
    const int tid = threadIdx.x;
    for (int i = tid; i < 96; i += 256)   W1[i] = w1[i];
    for (int i = tid; i < 32; i += 256) { S1[i] = s1[i]; B1[i] = b1[i]; S2[i] = s2[i]; B2[i] = b2[i]; }
    for (int i = tid; i < 1024; i += 256) W2[i] = w2[i];
    for (int i = tid; i < 2048; i += 256) W3[i] = w3[i];
    for (int i = tid; i < 64; i += 256) { S3[i] = s3[i]; B3[i] = b3[i]; }
    __syncthreads();

    const int n  = tid & 31;
    const int g  = blockIdx.x * 8 + (tid >> 5);   // centroid 0..8191
    const int b  = g >> 12;
    const size_t base = (size_t)g * KGN + n;
    const int   nj = nn_idx[base];
    const float nk = nn_key[base];

    const float* X = xyz + (size_t)b * NPTS * 3;
    const float gx = X[nj * 3 + 0] - newxyz[g * 3 + 0];
    const float gy = X[nj * 3 + 1] - newxyz[g * 3 + 1];
    const float gz = X[nj * 3 + 2] - newxyz[g * 3 + 2];

    float h1[32];
#pragma unroll
    for (int o = 0; o < 32; ++o) {
        float a = gx * W1[o * 3 + 0] + gy * W1[o * 3 + 1] + gz * W1[o * 3 + 2];
        h1[o] = fmaxf(a * S1[o] + B1[o], 0.0f);
    }
    float h2[32];
#pragma unroll
    for (int o = 0; o < 32; ++o) {
        float a = 0.0f;
#pragma unroll
        for (int k = 0; k < 32; ++k) a += h1[k] * W2[o * 32 + k];
        h2[o] = fmaxf(a * S2[o] + B2[o], 0.0f);
    }
    const bool valid = (sqrtf(nk) <= 0.8f);   // exact mask (sentinel FLT_MAX -> false)

    for (int o = 0; o < 64; ++o) {
        float a = 0.0f;
#pragma unroll
        for (int k = 0; k < 32; ++k) a += h2[k] * W3[o * 32 + k];
        float v = fmaxf(a * S3[o] + B3[o], 0.0f);
        v = valid ? v : -INFINITY;
#pragma unroll
        for (int off = 1; off < 32; off <<= 1) v = fmaxf(v, __shfl_xor(v, off));
        if (n == (o & 31)) FLout[(size_t)g * CLN + o] = v;
    }
}

// =====================================================================
// K4: DAM fusion (R3 verbatim). Wave per centroid, lane = channel.
// LDS-transposed 64x64 weights for conflict-free per-lane reads.
// =====================================================================
__global__ __launch_bounds__(256) void fuse_kernel(const float* __restrict__ pts_cam,
                                                   const float* __restrict__ FIn,
                                                   const float* __restrict__ tw1, const float* __restrict__ tb1,
                                                   const float* __restrict__ tw2, const float* __restrict__ tb2,
                                                   const float* __restrict__ tw3, const float* __restrict__ tb3,
                                                   const float* __restrict__ gw_raw, const float* __restrict__ gb_raw,
                                                   const float* __restrict__ gw_img, const float* __restrict__ gb_img,
                                                   const float* __restrict__ gw_lid, const float* __restrict__ gb_lid,
                                                   const float* __restrict__ uw, const float* __restrict__ ub,
                                                   const float* __restrict__ vw, const float* __restrict__ vb,
                                                   const int* __restrict__ fps_idx,
                                                   const float* __restrict__ newxyz,
                                                   const float* __restrict__ FLin,
                                                   float* __restrict__ out) {
    __shared__ float WIm[4096], WLi[4096], WT2[4096];
    const int tid = threadIdx.x;
    for (int i = tid; i < 4096; i += 256) {
        int c = i >> 6, k = i & 63;          // weight[c][k] -> transposed [k][c]
        WIm[k * 64 + c] = gw_img[i];
        WLi[k * 64 + c] = gw_lid[i];
        WT2[k * 64 + c] = tw2[i];
    }
    __syncthreads();

    const int lane = tid & 63;
    const int g    = blockIdx.x * 4 + (tid >> 6);   // centroid 0..8191
    const int b    = g >> 12;
    const int m    = g & (MPTS - 1);
    const int far  = fps_idx[g];

    const float fi_in = FIn[((size_t)(b * CIN + lane)) * NPTS + far];
    const float fl_in = FLin[(size_t)g * CLN + lane];
    const float nx = newxyz[g * 3 + 0], ny = newxyz[g * 3 + 1], nz = newxyz[g * 3 + 2];

    float fr = fmaxf(nx * gw_raw[lane * 3 + 0] + ny * gw_raw[lane * 3 + 1] +
                     nz * gw_raw[lane * 3 + 2] + gb_raw[lane], 0.0f);

    float ai = gb_img[lane], al = gb_lid[lane];
#pragma unroll 8
    for (int k = 0; k < 64; ++k) {
        float vi = __shfl(fi_in, k);
        float vl = __shfl(fl_in, k);
        ai += vi * WIm[k * 64 + lane];
        al += vl * WLi[k * 64 + lane];
    }
    const float s = tanhf(fr + fmaxf(ai, 0.0f) + fmaxf(al, 0.0f));

    // AdaptiveThresholdNet on constant density
    const float dens = (float)(64.0 / (4.0 / 3.0 * 3.14159 * 1.0));
    float t1 = fmaxf(dens * tw1[lane] + tb1[lane], 0.0f);
    float a2 = tb2[lane];
#pragma unroll 8
    for (int k = 0; k < 64; ++k) a2 += __shfl(t1, k) * WT2[k * 64 + lane];
    float t2 = fmaxf(a2, 0.0f);
    float a3 = wave_sum64(t2 * tw3[lane]) + tb3[0];
    float thr = 20.0f + 40.0f * (1.0f / (1.0f + expf(-a3)));

    float aI = wave_sum64(s * uw[lane]) + ub[0];
    float aL = wave_sum64(s * vw[lane]) + vb[0];
    float wIv = 1.0f / (1.0f + expf(-aI));
    float wLv = 1.0f / (1.0f + expf(-aL));

    const float z = pts_cam[((size_t)b * NPTS + far) * 3 + 2];
    const bool near = (z <= thr);

    const size_t o1 = ((size_t)(b * 128 + lane)) * MPTS + m;
    out[o1]                       = near ? fl_in        : fi_in;
    out[o1 + (size_t)64 * MPTS]   = near ? fi_in * wIv  : fl_in * wLv;
}

// =====================================================================
extern "C" void kernel_launch(void* const* d_in, const int* in_sizes, int n_in,
                              void* d_out, int out_size, void* d_ws, size_t ws_size,
                              hipStream_t stream) {
    const float* xyz     = (const float*)d_in[0];
    const float* pts_cam = (const float*)d_in[1];
    const float* FI      = (const float*)d_in[2];
    const float* w1 = (const float*)d_in[3];
    const float* s1 = (const float*)d_in[4];
    const float* b1 = (const float*)d_in[5];
    const float* w2 = (const float*)d_in[6];
    const float* s2 = (const float*)d_in[7];
    const float* b2 = (const float*)d_in[8];
    const float* w3 = (const float*)d_in[9];
    const float* s3 = (const float*)d_in[10];
    const float* b3 = (const float*)d_in[11];
    const float* tw1 = (const float*)d_in[12];
    const float* tb1 = (const float*)d_in[13];
    const float* tw2 = (const float*)d_in[14];
    const float* tb2 = (const float*)d_in[15];
    const float* tw3 = (const float*)d_in[16];
    const float* tb3 = (const float*)d_in[17];
    const float* gw_raw = (const float*)d_in[18];
    const float* gb_raw = (const float*)d_in[19];
    const float* gw_img = (const float*)d_in[20];
    const float* gb_img = (const float*)d_in[21];
    const float* gw_lid = (const float*)d_in[22];
    const float* gb_lid = (const float*)d_in[23];
    const float* uw = (const float*)d_in[24];
    const float* ub = (const float*)d_in[25];
    const float* vw = (const float*)d_in[26];
    const float* vb = (const float*)d_in[27];
    float* out = (float*)d_out;

    // workspace layout (bytes) — total 4,325,376.
    // pts4 is dead after knn; FL (written by mlp, later) aliases its region.
    char* ws = (char*)d_ws;
    int*    ws_idx    = (int*)   (ws + 0);         // 8192 ints    (32 KB)
    float*  ws_newxyz = (float*) (ws + 32768);     // 24576 f      (96 KB)  -> 131072
    float4* ws_pts4   = (float4*)(ws + 131072);    // 32768 float4 (512 KB) -> 655360 [dead after knn]
    float*  ws_FL     = (float*) (ws + 131072);    // 524288 f     (2 MB)   -> 2228224 [aliases pts4]
    int*    ws_nnidx  = (int*)   (ws + 2228224);   // 262144 ints  (1 MB)   -> 3276800
    float*  ws_nnkey  = (float*) (ws + 3276800);   // 262144 f     (1 MB)   -> 4325376
    (void)ws_size; (void)in_sizes; (void)n_in; (void)out_size;

    prep_kernel<<<(BN * NPTS) / 256, 256, 0, stream>>>(xyz, ws_pts4);
    fps_kernel<<<BN, 1024, 0, stream>>>(ws_pts4, ws_idx);
    knn_kernel<<<2048, 256, 0, stream>>>(ws_pts4, ws_idx, ws_newxyz, ws_nnidx, ws_nnkey);
    mlp_kernel<<<1024, 256, 0, stream>>>(xyz, w1, s1, b1, w2, s2, b2, w3, s3, b3,
                                         ws_newxyz, ws_nnidx, ws_nnkey, ws_FL);
    fuse_kernel<<<2048, 256, 0, stream>>>(pts_cam, FI, tw1, tb1, tw2, tb2, tw3, tb3,
                                          gw_raw, gb_raw, gw_img, gb_img, gw_lid, gb_lid,
                                          uw, ub, vw, vb, ws_idx, ws_newxyz, ws_FL, out);
}